// Round 1
// baseline (1484.317 us; speedup 1.0000x reference)
//
#include <hip/hip_runtime.h>

#define F 128
#define ROWS 64

__global__ void zero_kernel(float4* __restrict__ out, int n4) {
    int i = blockIdx.x * blockDim.x + threadIdx.x;
    if (i < n4) out[i] = make_float4(0.f, 0.f, 0.f, 0.f);
}

// One edge handled by 32 threads; each thread moves a float4 (4 feats) via 4 atomics.
__global__ void scatter_kernel(const float* __restrict__ feat,
                               const int* __restrict__ src,
                               const int* __restrict__ dst,
                               float* __restrict__ agg, int E) {
    int gid = blockIdx.x * blockDim.x + threadIdx.x;
    int e = gid >> 5;
    if (e >= E) return;
    int q = gid & 31;
    int s = src[e];
    int d = dst[e];
    const float4 v = ((const float4*)(feat + (size_t)s * F))[q];
    float* o = agg + (size_t)d * F + (q << 2);
    atomicAdd(o + 0, v.x);
    atomicAdd(o + 1, v.y);
    atomicAdd(o + 2, v.z);
    atomicAdd(o + 3, v.w);
}

// In-place h = relu(agg @ W^T + b). Each block owns ROWS full rows, so reading
// agg rows into LDS then overwriting them in global is race-free.
// LDS: sW (W transposed, padded 132 to kill the stride-128 bank conflict) 67.6 KB
//    + sA 33.8 KB  -> 101 KB -> 1 block/CU.
__global__ __launch_bounds__(256) void linear_relu_kernel(
        float* __restrict__ h, const float* __restrict__ W,
        const float* __restrict__ b, int N) {
    __shared__ __align__(16) float sW[F][132];   // sW[k][o] = W[o][k]
    __shared__ __align__(16) float sA[ROWS][132];
    const int tid = threadIdx.x;
    const int row0 = blockIdx.x * ROWS;

    // Stage W transposed. Writes: lanes vary k for fixed o -> addr k*132+o ->
    // banks (4k+o)%32, consecutive k -> distinct banks: conflict-free.
    for (int i = tid; i < F * F; i += 256) {
        int o = i >> 7, k = i & (F - 1);
        sW[k][o] = W[i];
    }
    // Stage A tile (float4 coalesced global reads).
    for (int i = tid; i < ROWS * (F / 4); i += 256) {
        int r = i >> 5, q = i & 31;
        int gr = row0 + r;
        float4 v = make_float4(0.f, 0.f, 0.f, 0.f);
        if (gr < N) v = ((const float4*)(h + (size_t)gr * F))[q];
        *((float4*)&sA[r][q << 2]) = v;
    }
    __syncthreads();

    const int tr = tid >> 5;   // 0..7  -> rows tr*8 .. tr*8+7
    const int tc = tid & 31;   // 0..31 -> cols tc*4 .. tc*4+3
    float acc[8][4];
#pragma unroll
    for (int i = 0; i < 8; ++i)
#pragma unroll
        for (int j = 0; j < 4; ++j) acc[i][j] = 0.f;

    for (int k = 0; k < F; k += 4) {
        const float4 w0 = *(const float4*)&sW[k + 0][tc << 2];
        const float4 w1 = *(const float4*)&sW[k + 1][tc << 2];
        const float4 w2 = *(const float4*)&sW[k + 2][tc << 2];
        const float4 w3 = *(const float4*)&sW[k + 3][tc << 2];
#pragma unroll
        for (int i = 0; i < 8; ++i) {
            const float4 a = *(const float4*)&sA[tr * 8 + i][k];  // broadcast read
            acc[i][0] += a.x * w0.x + a.y * w1.x + a.z * w2.x + a.w * w3.x;
            acc[i][1] += a.x * w0.y + a.y * w1.y + a.z * w2.y + a.w * w3.y;
            acc[i][2] += a.x * w0.z + a.y * w1.z + a.z * w2.z + a.w * w3.z;
            acc[i][3] += a.x * w0.w + a.y * w1.w + a.z * w2.w + a.w * w3.w;
        }
    }

    const float4 bias = *(const float4*)&b[tc << 2];
#pragma unroll
    for (int i = 0; i < 8; ++i) {
        int gr = row0 + tr * 8 + i;
        if (gr < N) {
            float4 o;
            o.x = fmaxf(acc[i][0] + bias.x, 0.f);
            o.y = fmaxf(acc[i][1] + bias.y, 0.f);
            o.z = fmaxf(acc[i][2] + bias.z, 0.f);
            o.w = fmaxf(acc[i][3] + bias.w, 0.f);
            ((float4*)(h + (size_t)gr * F))[tc] = o;
        }
    }
}

extern "C" void kernel_launch(void* const* d_in, const int* in_sizes, int n_in,
                              void* d_out, int out_size, void* d_ws, size_t ws_size,
                              hipStream_t stream) {
    const float* feat = (const float*)d_in[0];
    const int*   src  = (const int*)d_in[1];
    const int*   dst  = (const int*)d_in[2];
    const float* W    = (const float*)d_in[3];
    const float* b    = (const float*)d_in[4];
    float* out = (float*)d_out;

    const int N = in_sizes[0] / F;   // 50000
    const int E = in_sizes[1];       // 800000

    const int n4 = N * (F / 4);
    zero_kernel<<<(n4 + 255) / 256, 256, 0, stream>>>((float4*)out, n4);

    const int sthreads = E * 32;
    scatter_kernel<<<(sthreads + 255) / 256, 256, 0, stream>>>(feat, src, dst, out, E);

    linear_relu_kernel<<<(N + ROWS - 1) / ROWS, 256, 0, stream>>>(out, W, b, N);
}

// Round 4
// 399.072 us; speedup vs baseline: 3.7194x; 3.7194x over previous
//
#include <hip/hip_runtime.h>

#define F 128
#define ROWS 64

__global__ void zero_int_kernel(int* __restrict__ p, int n) {
    int i = blockIdx.x * blockDim.x + threadIdx.x;
    if (i < n) p[i] = 0;
}

__global__ void zero_f4_kernel(float4* __restrict__ out, int n4) {
    int i = blockIdx.x * blockDim.x + threadIdx.x;
    if (i < n4) out[i] = make_float4(0.f, 0.f, 0.f, 0.f);
}

__global__ void hist_kernel(const int* __restrict__ dst, int* __restrict__ counts, int E) {
    int e = blockIdx.x * blockDim.x + threadIdx.x;
    if (e < E) atomicAdd(&counts[dst[e]], 1);
}

// Single-block (256-thread) exclusive scan: counts[0..N) -> offsets[0..N] + cursor copy.
__global__ __launch_bounds__(256) void scan_kernel(const int* __restrict__ counts,
                                                   int* __restrict__ offsets,
                                                   int* __restrict__ cursor, int N) {
    __shared__ int part[256];
    const int tid = threadIdx.x;
    const int chunk = (N + 255) / 256;
    const int begin = min(tid * chunk, N);
    const int endi = min(begin + chunk, N);
    int s = 0;
    for (int i = begin; i < endi; ++i) s += counts[i];
    part[tid] = s;
    __syncthreads();
    for (int off = 1; off < 256; off <<= 1) {
        int t = (tid >= off) ? part[tid - off] : 0;
        __syncthreads();
        part[tid] += t;
        __syncthreads();
    }
    int run = part[tid] - s;  // exclusive prefix at this thread's chunk start
    for (int i = begin; i < endi; ++i) {
        int c = counts[i];
        offsets[i] = run;
        cursor[i] = run;
        run += c;
    }
    if (tid == 255) offsets[N] = part[255];
}

__global__ void place_kernel(const int* __restrict__ src, const int* __restrict__ dst,
                             int* __restrict__ cursor, int* __restrict__ ssrc, int E) {
    int e = blockIdx.x * blockDim.x + threadIdx.x;
    if (e < E) {
        int pos = atomicAdd(&cursor[dst[e]], 1);
        ssrc[pos] = src[e];
    }
}

// One wave per node: accumulate 128 feats (float2/lane) in registers, write once.
__global__ __launch_bounds__(256) void agg_kernel(const float* __restrict__ feat,
                                                  const int* __restrict__ ssrc,
                                                  const int* __restrict__ offs,
                                                  float* __restrict__ out, int N) {
    const int gwave = (blockIdx.x * blockDim.x + threadIdx.x) >> 6;
    const int lane = threadIdx.x & 63;
    const int nwaves = (gridDim.x * blockDim.x) >> 6;
    for (int v = gwave; v < N; v += nwaves) {
        const int s0 = offs[v], s1 = offs[v + 1];
        float ax = 0.f, ay = 0.f;
        int e = s0;
        for (; e + 4 <= s1; e += 4) {
            int i0 = ssrc[e], i1 = ssrc[e + 1], i2 = ssrc[e + 2], i3 = ssrc[e + 3];
            const float2 f0 = *(const float2*)&feat[(size_t)i0 * F + lane * 2];
            const float2 f1 = *(const float2*)&feat[(size_t)i1 * F + lane * 2];
            const float2 f2 = *(const float2*)&feat[(size_t)i2 * F + lane * 2];
            const float2 f3 = *(const float2*)&feat[(size_t)i3 * F + lane * 2];
            ax += (f0.x + f1.x) + (f2.x + f3.x);
            ay += (f0.y + f1.y) + (f2.y + f3.y);
        }
        for (; e < s1; ++e) {
            int i0 = ssrc[e];
            const float2 f0 = *(const float2*)&feat[(size_t)i0 * F + lane * 2];
            ax += f0.x;
            ay += f0.y;
        }
        float2 r;
        r.x = ax;
        r.y = ay;
        *(float2*)&out[(size_t)v * F + lane * 2] = r;
    }
}

// Fallback path (only if ws too small): direct fp32 atomic scatter (R1-proven).
__global__ void scatter_atomic_kernel(const float* __restrict__ feat,
                                      const int* __restrict__ src,
                                      const int* __restrict__ dst,
                                      float* __restrict__ agg, int E) {
    int gid = blockIdx.x * blockDim.x + threadIdx.x;
    int e = gid >> 5;
    if (e >= E) return;
    int q = gid & 31;
    int s = src[e];
    int d = dst[e];
    const float4 v = ((const float4*)(feat + (size_t)s * F))[q];
    float* o = agg + (size_t)d * F + (q << 2);
    atomicAdd(o + 0, v.x);
    atomicAdd(o + 1, v.y);
    atomicAdd(o + 2, v.z);
    atomicAdd(o + 3, v.w);
}

// In-place h = relu(agg @ W^T + b). Only the A tile lives in LDS (33.8 KB ->
// 4 blocks/CU); W (64 KB) read from global, L1/L2-resident.
__global__ __launch_bounds__(256) void linear_relu_kernel(
        float* __restrict__ h, const float* __restrict__ W,
        const float* __restrict__ b, int N) {
    __shared__ __align__(16) float sA[ROWS][132];
    const int tid = threadIdx.x;
    const int row0 = blockIdx.x * ROWS;

    for (int i = tid; i < ROWS * (F / 4); i += 256) {
        int r = i >> 5, q = i & 31;
        int gr = row0 + r;
        float4 v = make_float4(0.f, 0.f, 0.f, 0.f);
        if (gr < N) v = ((const float4*)(h + (size_t)gr * F))[q];
        *((float4*)&sA[r][q << 2]) = v;
    }
    __syncthreads();

    const int tr = tid >> 5;   // 0..7  -> rows tr*8 .. tr*8+7
    const int tc = tid & 31;   // 0..31 -> cols tc*4 .. tc*4+3
    float acc[8][4];
#pragma unroll
    for (int i = 0; i < 8; ++i)
#pragma unroll
        for (int j = 0; j < 4; ++j) acc[i][j] = 0.f;

    const float* Wr0 = W + (size_t)(tc * 4 + 0) * F;
    const float* Wr1 = W + (size_t)(tc * 4 + 1) * F;
    const float* Wr2 = W + (size_t)(tc * 4 + 2) * F;
    const float* Wr3 = W + (size_t)(tc * 4 + 3) * F;

    for (int k = 0; k < F; k += 4) {
        const float4 w0 = *(const float4*)&Wr0[k];
        const float4 w1 = *(const float4*)&Wr1[k];
        const float4 w2 = *(const float4*)&Wr2[k];
        const float4 w3 = *(const float4*)&Wr3[k];
#pragma unroll
        for (int i = 0; i < 8; ++i) {
            const float4 a = *(const float4*)&sA[tr * 8 + i][k];  // broadcast read
            acc[i][0] += a.x * w0.x + a.y * w0.y + a.z * w0.z + a.w * w0.w;
            acc[i][1] += a.x * w1.x + a.y * w1.y + a.z * w1.z + a.w * w1.w;
            acc[i][2] += a.x * w2.x + a.y * w2.y + a.z * w2.z + a.w * w2.w;
            acc[i][3] += a.x * w3.x + a.y * w3.y + a.z * w3.z + a.w * w3.w;
        }
    }

    const float4 bias = *(const float4*)&b[tc << 2];
#pragma unroll
    for (int i = 0; i < 8; ++i) {
        int gr = row0 + tr * 8 + i;
        if (gr < N) {
            float4 o;
            o.x = fmaxf(acc[i][0] + bias.x, 0.f);
            o.y = fmaxf(acc[i][1] + bias.y, 0.f);
            o.z = fmaxf(acc[i][2] + bias.z, 0.f);
            o.w = fmaxf(acc[i][3] + bias.w, 0.f);
            ((float4*)(h + (size_t)gr * F))[tc] = o;
        }
    }
}

extern "C" void kernel_launch(void* const* d_in, const int* in_sizes, int n_in,
                              void* d_out, int out_size, void* d_ws, size_t ws_size,
                              hipStream_t stream) {
    const float* feat = (const float*)d_in[0];
    const int*   src  = (const int*)d_in[1];
    const int*   dst  = (const int*)d_in[2];
    const float* W    = (const float*)d_in[3];
    const float* b    = (const float*)d_in[4];
    float* out = (float*)d_out;

    const int N = in_sizes[0] / F;   // 50000
    const int E = in_sizes[1];       // 800000

    // ws layout (ints): counts[N] | offsets[N+1] | cursor[N] | ssrc[E]  ~3.8 MB
    const size_t ws_needed = (size_t)(N + (N + 1) + N + E) * sizeof(int);

    if (ws_size >= ws_needed) {
        int* counts  = (int*)d_ws;
        int* offsets = counts + N;
        int* cursor  = offsets + (N + 1);
        int* ssrc    = cursor + N;

        zero_int_kernel<<<(N + 255) / 256, 256, 0, stream>>>(counts, N);
        hist_kernel<<<(E + 255) / 256, 256, 0, stream>>>(dst, counts, E);
        scan_kernel<<<1, 256, 0, stream>>>(counts, offsets, cursor, N);
        place_kernel<<<(E + 255) / 256, 256, 0, stream>>>(src, dst, cursor, ssrc, E);
        agg_kernel<<<2048, 256, 0, stream>>>(feat, ssrc, offsets, out, N);
    } else {
        // Workspace too small for CSR sort: proven atomic-scatter fallback.
        const int n4 = N * (F / 4);
        zero_f4_kernel<<<(n4 + 255) / 256, 256, 0, stream>>>((float4*)out, n4);
        const int sthreads = E * 32;
        scatter_atomic_kernel<<<(sthreads + 255) / 256, 256, 0, stream>>>(feat, src, dst, out, E);
    }

    linear_relu_kernel<<<(N + ROWS - 1) / ROWS, 256, 0, stream>>>(out, W, b, N);
}

// Round 6
// 297.550 us; speedup vs baseline: 4.9885x; 1.3412x over previous
//
#include <hip/hip_runtime.h>

#define F 128
#define ROWS 64
#define SCAN_TILE 1024

__global__ void zero_int_kernel(int* __restrict__ p, int n) {
    int i = blockIdx.x * blockDim.x + threadIdx.x;
    if (i < n) p[i] = 0;
}

__global__ void zero_f4_kernel(float4* __restrict__ out, int n4) {
    int i = blockIdx.x * blockDim.x + threadIdx.x;
    if (i < n4) out[i] = make_float4(0.f, 0.f, 0.f, 0.f);
}

__global__ void hist_kernel(const int* __restrict__ dst, int* __restrict__ counts, int E) {
    int e = blockIdx.x * blockDim.x + threadIdx.x;
    if (e < E) atomicAdd(&counts[dst[e]], 1);
}

// Two-level scan. scan1: per-tile (1024 elems) exclusive scan + tile totals.
__global__ __launch_bounds__(256) void scan1_kernel(const int* __restrict__ counts,
                                                    int* __restrict__ offsets,
                                                    int* __restrict__ blockSums, int N) {
    __shared__ int lds[256];
    const int tid = threadIdx.x;
    const int i0 = blockIdx.x * SCAN_TILE + tid * 4;
    int v[4];
    int s = 0;
#pragma unroll
    for (int j = 0; j < 4; ++j) {
        int i = i0 + j;
        v[j] = (i < N) ? counts[i] : 0;
        s += v[j];
    }
    lds[tid] = s;
    __syncthreads();
    for (int off = 1; off < 256; off <<= 1) {
        int t = (tid >= off) ? lds[tid - off] : 0;
        __syncthreads();
        lds[tid] += t;
        __syncthreads();
    }
    int excl = lds[tid] - s;  // exclusive prefix within tile
#pragma unroll
    for (int j = 0; j < 4; ++j) {
        int i = i0 + j;
        if (i < N) offsets[i] = excl;
        excl += v[j];
    }
    if (tid == 255) blockSums[blockIdx.x] = lds[255];
}

// scan2: exclusive scan of <=256 tile totals; also writes grand total to offsets[N].
__global__ __launch_bounds__(256) void scan2_kernel(int* __restrict__ blockSums,
                                                    int* __restrict__ offsets, int NB, int N) {
    __shared__ int lds[256];
    const int tid = threadIdx.x;
    int s = (tid < NB) ? blockSums[tid] : 0;
    lds[tid] = s;
    __syncthreads();
    for (int off = 1; off < 256; off <<= 1) {
        int t = (tid >= off) ? lds[tid - off] : 0;
        __syncthreads();
        lds[tid] += t;
        __syncthreads();
    }
    if (tid < NB) blockSums[tid] = lds[tid] - s;  // exclusive tile prefix
    if (tid == 255) offsets[N] = lds[255];        // grand total == E
}

// scan3: add tile prefix, materialize offsets + cursor.
__global__ __launch_bounds__(256) void scan3_kernel(int* __restrict__ offsets,
                                                    int* __restrict__ cursor,
                                                    const int* __restrict__ blockSums, int N) {
    int i = blockIdx.x * blockDim.x + threadIdx.x;
    if (i < N) {
        int o = offsets[i] + blockSums[i / SCAN_TILE];
        offsets[i] = o;
        cursor[i] = o;
    }
}

__global__ void place_kernel(const int* __restrict__ src, const int* __restrict__ dst,
                             int* __restrict__ cursor, int* __restrict__ ssrc, int E) {
    int e = blockIdx.x * blockDim.x + threadIdx.x;
    if (e < E) {
        int pos = atomicAdd(&cursor[dst[e]], 1);
        ssrc[pos] = src[e];
    }
}

// One wave per node: accumulate 128 feats (float2/lane) in registers, write once.
__global__ __launch_bounds__(256) void agg_kernel(const float* __restrict__ feat,
                                                  const int* __restrict__ ssrc,
                                                  const int* __restrict__ offs,
                                                  float* __restrict__ out, int N) {
    const int gwave = (blockIdx.x * blockDim.x + threadIdx.x) >> 6;
    const int lane = threadIdx.x & 63;
    const int nwaves = (gridDim.x * blockDim.x) >> 6;
    for (int v = gwave; v < N; v += nwaves) {
        const int s0 = offs[v], s1 = offs[v + 1];
        float ax = 0.f, ay = 0.f;
        int e = s0;
        for (; e + 4 <= s1; e += 4) {
            int i0 = ssrc[e], i1 = ssrc[e + 1], i2 = ssrc[e + 2], i3 = ssrc[e + 3];
            const float2 f0 = *(const float2*)&feat[(size_t)i0 * F + lane * 2];
            const float2 f1 = *(const float2*)&feat[(size_t)i1 * F + lane * 2];
            const float2 f2 = *(const float2*)&feat[(size_t)i2 * F + lane * 2];
            const float2 f3 = *(const float2*)&feat[(size_t)i3 * F + lane * 2];
            ax += (f0.x + f1.x) + (f2.x + f3.x);
            ay += (f0.y + f1.y) + (f2.y + f3.y);
        }
        for (; e < s1; ++e) {
            int i0 = ssrc[e];
            const float2 f0 = *(const float2*)&feat[(size_t)i0 * F + lane * 2];
            ax += f0.x;
            ay += f0.y;
        }
        float2 r;
        r.x = ax;
        r.y = ay;
        *(float2*)&out[(size_t)v * F + lane * 2] = r;
    }
}

// Fallback path (only if ws too small): direct fp32 atomic scatter (R1-proven).
__global__ void scatter_atomic_kernel(const float* __restrict__ feat,
                                      const int* __restrict__ src,
                                      const int* __restrict__ dst,
                                      float* __restrict__ agg, int E) {
    int gid = blockIdx.x * blockDim.x + threadIdx.x;
    int e = gid >> 5;
    if (e >= E) return;
    int q = gid & 31;
    int s = src[e];
    int d = dst[e];
    const float4 v = ((const float4*)(feat + (size_t)s * F))[q];
    float* o = agg + (size_t)d * F + (q << 2);
    atomicAdd(o + 0, v.x);
    atomicAdd(o + 1, v.y);
    atomicAdd(o + 2, v.z);
    atomicAdd(o + 3, v.w);
}

// In-place h = relu(agg @ W^T + b). Only the A tile lives in LDS (33.8 KB ->
// 4 blocks/CU); W (64 KB) read from global, L1/L2-resident.
__global__ __launch_bounds__(256) void linear_relu_kernel(
        float* __restrict__ h, const float* __restrict__ W,
        const float* __restrict__ b, int N) {
    __shared__ __align__(16) float sA[ROWS][132];
    const int tid = threadIdx.x;
    const int row0 = blockIdx.x * ROWS;

    for (int i = tid; i < ROWS * (F / 4); i += 256) {
        int r = i >> 5, q = i & 31;
        int gr = row0 + r;
        float4 v = make_float4(0.f, 0.f, 0.f, 0.f);
        if (gr < N) v = ((const float4*)(h + (size_t)gr * F))[q];
        *((float4*)&sA[r][q << 2]) = v;
    }
    __syncthreads();

    const int tr = tid >> 5;   // 0..7
    const int tc = tid & 31;   // 0..31
    float acc[8][4];
#pragma unroll
    for (int i = 0; i < 8; ++i)
#pragma unroll
        for (int j = 0; j < 4; ++j) acc[i][j] = 0.f;

    const float* Wr0 = W + (size_t)(tc * 4 + 0) * F;
    const float* Wr1 = W + (size_t)(tc * 4 + 1) * F;
    const float* Wr2 = W + (size_t)(tc * 4 + 2) * F;
    const float* Wr3 = W + (size_t)(tc * 4 + 3) * F;

    for (int k = 0; k < F; k += 4) {
        const float4 w0 = *(const float4*)&Wr0[k];
        const float4 w1 = *(const float4*)&Wr1[k];
        const float4 w2 = *(const float4*)&Wr2[k];
        const float4 w3 = *(const float4*)&Wr3[k];
#pragma unroll
        for (int i = 0; i < 8; ++i) {
            const float4 a = *(const float4*)&sA[tr * 8 + i][k];
            acc[i][0] += a.x * w0.x + a.y * w0.y + a.z * w0.z + a.w * w0.w;
            acc[i][1] += a.x * w1.x + a.y * w1.y + a.z * w1.z + a.w * w1.w;
            acc[i][2] += a.x * w2.x + a.y * w2.y + a.z * w2.z + a.w * w2.w;
            acc[i][3] += a.x * w3.x + a.y * w3.y + a.z * w3.z + a.w * w3.w;
        }
    }

    const float4 bias = *(const float4*)&b[tc << 2];
#pragma unroll
    for (int i = 0; i < 8; ++i) {
        int gr = row0 + tr * 8 + i;
        if (gr < N) {
            float4 o;
            o.x = fmaxf(acc[i][0] + bias.x, 0.f);
            o.y = fmaxf(acc[i][1] + bias.y, 0.f);
            o.z = fmaxf(acc[i][2] + bias.z, 0.f);
            o.w = fmaxf(acc[i][3] + bias.w, 0.f);
            ((float4*)(h + (size_t)gr * F))[tc] = o;
        }
    }
}

extern "C" void kernel_launch(void* const* d_in, const int* in_sizes, int n_in,
                              void* d_out, int out_size, void* d_ws, size_t ws_size,
                              hipStream_t stream) {
    const float* feat = (const float*)d_in[0];
    const int*   src  = (const int*)d_in[1];
    const int*   dst  = (const int*)d_in[2];
    const float* W    = (const float*)d_in[3];
    const float* b    = (const float*)d_in[4];
    float* out = (float*)d_out;

    const int N = in_sizes[0] / F;   // 50000
    const int E = in_sizes[1];       // 800000
    const int NB = (N + SCAN_TILE - 1) / SCAN_TILE;  // 49 (must be <= 256)

    // ws layout (ints): counts[N] | offsets[N+1] | cursor[N] | blockSums[256] | ssrc[E]
    const size_t ws_needed = (size_t)(N + (N + 1) + N + 256 + E) * sizeof(int);

    if (ws_size >= ws_needed && NB <= 256) {
        int* counts    = (int*)d_ws;
        int* offsets   = counts + N;
        int* cursor    = offsets + (N + 1);
        int* blockSums = cursor + N;
        int* ssrc      = blockSums + 256;

        zero_int_kernel<<<(N + 255) / 256, 256, 0, stream>>>(counts, N);
        hist_kernel<<<(E + 255) / 256, 256, 0, stream>>>(dst, counts, E);
        scan1_kernel<<<NB, 256, 0, stream>>>(counts, offsets, blockSums, N);
        scan2_kernel<<<1, 256, 0, stream>>>(blockSums, offsets, NB, N);
        scan3_kernel<<<(N + 255) / 256, 256, 0, stream>>>(offsets, cursor, blockSums, N);
        place_kernel<<<(E + 255) / 256, 256, 0, stream>>>(src, dst, cursor, ssrc, E);
        agg_kernel<<<2048, 256, 0, stream>>>(feat, ssrc, offsets, out, N);
    } else {
        // Workspace too small for CSR sort: proven atomic-scatter fallback.
        const int n4 = N * (F / 4);
        zero_f4_kernel<<<(n4 + 255) / 256, 256, 0, stream>>>((float4*)out, n4);
        const int sthreads = E * 32;
        scatter_atomic_kernel<<<(sthreads + 255) / 256, 256, 0, stream>>>(feat, src, dst, out, E);
    }

    linear_relu_kernel<<<(N + ROWS - 1) / ROWS, 256, 0, stream>>>(out, W, b, N);
}

// Round 7
// 269.589 us; speedup vs baseline: 5.5059x; 1.1037x over previous
//
#include <hip/hip_runtime.h>

#define F 128
#define ROWS2 32
#define SCAN_TILE 1024

__global__ void zero_int_kernel(int* __restrict__ p, int n) {
    int i = blockIdx.x * blockDim.x + threadIdx.x;
    if (i < n) p[i] = 0;
}

__global__ void zero_f4_kernel(float4* __restrict__ out, int n4) {
    int i = blockIdx.x * blockDim.x + threadIdx.x;
    if (i < n4) out[i] = make_float4(0.f, 0.f, 0.f, 0.f);
}

// wT[k][o] = W[o][k]  (128x128, one-shot, ~2us)
__global__ void transpose_w_kernel(const float* __restrict__ W, float* __restrict__ wT) {
    int i = blockIdx.x * 256 + threadIdx.x;  // 64 blocks x 256 = 16384
    int o = i >> 7, k = i & 127;
    wT[k * F + o] = W[i];
}

__global__ void hist_kernel(const int* __restrict__ dst, int* __restrict__ counts, int E) {
    int e = blockIdx.x * blockDim.x + threadIdx.x;
    if (e < E) atomicAdd(&counts[dst[e]], 1);
}

// Two-level scan. scan1: per-tile (1024 elems) exclusive scan + tile totals.
__global__ __launch_bounds__(256) void scan1_kernel(const int* __restrict__ counts,
                                                    int* __restrict__ offsets,
                                                    int* __restrict__ blockSums, int N) {
    __shared__ int lds[256];
    const int tid = threadIdx.x;
    const int i0 = blockIdx.x * SCAN_TILE + tid * 4;
    int v[4];
    int s = 0;
#pragma unroll
    for (int j = 0; j < 4; ++j) {
        int i = i0 + j;
        v[j] = (i < N) ? counts[i] : 0;
        s += v[j];
    }
    lds[tid] = s;
    __syncthreads();
    for (int off = 1; off < 256; off <<= 1) {
        int t = (tid >= off) ? lds[tid - off] : 0;
        __syncthreads();
        lds[tid] += t;
        __syncthreads();
    }
    int excl = lds[tid] - s;
#pragma unroll
    for (int j = 0; j < 4; ++j) {
        int i = i0 + j;
        if (i < N) offsets[i] = excl;
        excl += v[j];
    }
    if (tid == 255) blockSums[blockIdx.x] = lds[255];
}

__global__ __launch_bounds__(256) void scan2_kernel(int* __restrict__ blockSums,
                                                    int* __restrict__ offsets, int NB, int N) {
    __shared__ int lds[256];
    const int tid = threadIdx.x;
    int s = (tid < NB) ? blockSums[tid] : 0;
    lds[tid] = s;
    __syncthreads();
    for (int off = 1; off < 256; off <<= 1) {
        int t = (tid >= off) ? lds[tid - off] : 0;
        __syncthreads();
        lds[tid] += t;
        __syncthreads();
    }
    if (tid < NB) blockSums[tid] = lds[tid] - s;
    if (tid == 255) offsets[N] = lds[255];
}

__global__ __launch_bounds__(256) void scan3_kernel(int* __restrict__ offsets,
                                                    int* __restrict__ cursor,
                                                    const int* __restrict__ blockSums, int N) {
    int i = blockIdx.x * blockDim.x + threadIdx.x;
    if (i < N) {
        int o = offsets[i] + blockSums[i / SCAN_TILE];
        offsets[i] = o;
        cursor[i] = o;
    }
}

__global__ void place_kernel(const int* __restrict__ src, const int* __restrict__ dst,
                             int* __restrict__ cursor, int* __restrict__ ssrc, int E) {
    int e = blockIdx.x * blockDim.x + threadIdx.x;
    if (e < E) {
        int pos = atomicAdd(&cursor[dst[e]], 1);
        ssrc[pos] = src[e];
    }
}

// One wave per node; half-wave pairs process alternate edges with float4 loads,
// combined via cross-half shuffle. Lanes 0-31 write the float4 row.
__global__ __launch_bounds__(256) void agg_kernel(const float* __restrict__ feat,
                                                  const int* __restrict__ ssrc,
                                                  const int* __restrict__ offs,
                                                  float* __restrict__ out, int N) {
    const int gwave = (blockIdx.x * blockDim.x + threadIdx.x) >> 6;
    const int lane = threadIdx.x & 63;
    const int half = lane >> 5;   // which edge of each pair
    const int q = lane & 31;      // float4 index within the 128-float row
    const int nwaves = (gridDim.x * blockDim.x) >> 6;
    const float4* feat4 = (const float4*)feat;
    for (int v = gwave; v < N; v += nwaves) {
        const int s0 = offs[v], s1 = offs[v + 1];
        float ax = 0.f, ay = 0.f, az = 0.f, aw = 0.f;
        int e = s0 + half;
        for (; e + 6 < s1; e += 8) {   // 4 edges per half = 8 edges/wave/iter
            int i0 = ssrc[e], i1 = ssrc[e + 2], i2 = ssrc[e + 4], i3 = ssrc[e + 6];
            const float4 f0 = feat4[(size_t)i0 * 32 + q];
            const float4 f1 = feat4[(size_t)i1 * 32 + q];
            const float4 f2 = feat4[(size_t)i2 * 32 + q];
            const float4 f3 = feat4[(size_t)i3 * 32 + q];
            ax += (f0.x + f1.x) + (f2.x + f3.x);
            ay += (f0.y + f1.y) + (f2.y + f3.y);
            az += (f0.z + f1.z) + (f2.z + f3.z);
            aw += (f0.w + f1.w) + (f2.w + f3.w);
        }
        for (; e < s1; e += 2) {
            const float4 f0 = feat4[(size_t)ssrc[e] * 32 + q];
            ax += f0.x; ay += f0.y; az += f0.z; aw += f0.w;
        }
        ax += __shfl_xor(ax, 32);
        ay += __shfl_xor(ay, 32);
        az += __shfl_xor(az, 32);
        aw += __shfl_xor(aw, 32);
        if (half == 0) {
            float4 r;
            r.x = ax; r.y = ay; r.z = az; r.w = aw;
            ((float4*)(out + (size_t)v * F))[q] = r;
        }
    }
}

// Fallback path (only if ws too small): direct fp32 atomic scatter (R1-proven).
__global__ void scatter_atomic_kernel(const float* __restrict__ feat,
                                      const int* __restrict__ src,
                                      const int* __restrict__ dst,
                                      float* __restrict__ agg, int E) {
    int gid = blockIdx.x * blockDim.x + threadIdx.x;
    int e = gid >> 5;
    if (e >= E) return;
    int q = gid & 31;
    int s = src[e];
    int d = dst[e];
    const float4 v = ((const float4*)(feat + (size_t)s * F))[q];
    float* o = agg + (size_t)d * F + (q << 2);
    atomicAdd(o + 0, v.x);
    atomicAdd(o + 1, v.y);
    atomicAdd(o + 2, v.z);
    atomicAdd(o + 3, v.w);
}

// In-place h = relu(agg @ W^T + b), reading pre-transposed wT (coalesced).
// sA 32x132 = 16.9 KB -> 6 resident blocks/CU at grid 1563 -> 24 waves/CU.
__global__ __launch_bounds__(256) void linear_relu_kernel(
        float* __restrict__ h, const float* __restrict__ wT,
        const float* __restrict__ b, int N) {
    __shared__ __align__(16) float sA[ROWS2][132];
    const int tid = threadIdx.x;
    const int row0 = blockIdx.x * ROWS2;

    for (int i = tid; i < ROWS2 * 32; i += 256) {
        int r = i >> 5, q = i & 31;
        int gr = row0 + r;
        float4 v = make_float4(0.f, 0.f, 0.f, 0.f);
        if (gr < N) v = ((const float4*)(h + (size_t)gr * F))[q];
        *((float4*)&sA[r][q << 2]) = v;
    }
    __syncthreads();

    const int tr = tid >> 5;   // 0..7 -> rows tr*4 .. tr*4+3
    const int tc = tid & 31;   // cols tc*4 .. tc*4+3
    float acc[4][4];
#pragma unroll
    for (int i = 0; i < 4; ++i)
#pragma unroll
        for (int j = 0; j < 4; ++j) acc[i][j] = 0.f;

    const float4* wT4 = (const float4*)wT;
    for (int k = 0; k < F; k += 4) {
        // w{d}.j = wT[k+d][tc*4+j] = W[tc*4+j][k+d]; coalesced in tc.
        const float4 w0 = wT4[(k + 0) * 32 + tc];
        const float4 w1 = wT4[(k + 1) * 32 + tc];
        const float4 w2 = wT4[(k + 2) * 32 + tc];
        const float4 w3 = wT4[(k + 3) * 32 + tc];
#pragma unroll
        for (int i = 0; i < 4; ++i) {
            const float4 a = *(const float4*)&sA[tr * 4 + i][k];  // broadcast
            acc[i][0] += a.x * w0.x + a.y * w1.x + a.z * w2.x + a.w * w3.x;
            acc[i][1] += a.x * w0.y + a.y * w1.y + a.z * w2.y + a.w * w3.y;
            acc[i][2] += a.x * w0.z + a.y * w1.z + a.z * w2.z + a.w * w3.z;
            acc[i][3] += a.x * w0.w + a.y * w1.w + a.z * w2.w + a.w * w3.w;
        }
    }

    const float4 bias = ((const float4*)b)[tc];
#pragma unroll
    for (int i = 0; i < 4; ++i) {
        int gr = row0 + tr * 4 + i;
        if (gr < N) {
            float4 o;
            o.x = fmaxf(acc[i][0] + bias.x, 0.f);
            o.y = fmaxf(acc[i][1] + bias.y, 0.f);
            o.z = fmaxf(acc[i][2] + bias.z, 0.f);
            o.w = fmaxf(acc[i][3] + bias.w, 0.f);
            ((float4*)(h + (size_t)gr * F))[tc] = o;
        }
    }
}

// Fallback linear (R6 version): reads W directly, 64-row tile.
__global__ __launch_bounds__(256) void linear_relu_w_kernel(
        float* __restrict__ h, const float* __restrict__ W,
        const float* __restrict__ b, int N) {
    __shared__ __align__(16) float sA[64][132];
    const int tid = threadIdx.x;
    const int row0 = blockIdx.x * 64;

    for (int i = tid; i < 64 * 32; i += 256) {
        int r = i >> 5, q = i & 31;
        int gr = row0 + r;
        float4 v = make_float4(0.f, 0.f, 0.f, 0.f);
        if (gr < N) v = ((const float4*)(h + (size_t)gr * F))[q];
        *((float4*)&sA[r][q << 2]) = v;
    }
    __syncthreads();

    const int tr = tid >> 5;
    const int tc = tid & 31;
    float acc[8][4];
#pragma unroll
    for (int i = 0; i < 8; ++i)
#pragma unroll
        for (int j = 0; j < 4; ++j) acc[i][j] = 0.f;

    const float* Wr0 = W + (size_t)(tc * 4 + 0) * F;
    const float* Wr1 = W + (size_t)(tc * 4 + 1) * F;
    const float* Wr2 = W + (size_t)(tc * 4 + 2) * F;
    const float* Wr3 = W + (size_t)(tc * 4 + 3) * F;

    for (int k = 0; k < F; k += 4) {
        const float4 w0 = *(const float4*)&Wr0[k];
        const float4 w1 = *(const float4*)&Wr1[k];
        const float4 w2 = *(const float4*)&Wr2[k];
        const float4 w3 = *(const float4*)&Wr3[k];
#pragma unroll
        for (int i = 0; i < 8; ++i) {
            const float4 a = *(const float4*)&sA[tr * 8 + i][k];
            acc[i][0] += a.x * w0.x + a.y * w0.y + a.z * w0.z + a.w * w0.w;
            acc[i][1] += a.x * w1.x + a.y * w1.y + a.z * w1.z + a.w * w1.w;
            acc[i][2] += a.x * w2.x + a.y * w2.y + a.z * w2.z + a.w * w2.w;
            acc[i][3] += a.x * w3.x + a.y * w3.y + a.z * w3.z + a.w * w3.w;
        }
    }

    const float4 bias = ((const float4*)b)[tc];
#pragma unroll
    for (int i = 0; i < 8; ++i) {
        int gr = row0 + tr * 8 + i;
        if (gr < N) {
            float4 o;
            o.x = fmaxf(acc[i][0] + bias.x, 0.f);
            o.y = fmaxf(acc[i][1] + bias.y, 0.f);
            o.z = fmaxf(acc[i][2] + bias.z, 0.f);
            o.w = fmaxf(acc[i][3] + bias.w, 0.f);
            ((float4*)(h + (size_t)gr * F))[tc] = o;
        }
    }
}

extern "C" void kernel_launch(void* const* d_in, const int* in_sizes, int n_in,
                              void* d_out, int out_size, void* d_ws, size_t ws_size,
                              hipStream_t stream) {
    const float* feat = (const float*)d_in[0];
    const int*   src  = (const int*)d_in[1];
    const int*   dst  = (const int*)d_in[2];
    const float* W    = (const float*)d_in[3];
    const float* b    = (const float*)d_in[4];
    float* out = (float*)d_out;

    const int N = in_sizes[0] / F;   // 50000
    const int E = in_sizes[1];       // 800000
    const int NB = (N + SCAN_TILE - 1) / SCAN_TILE;  // 49 (<=256)

    // ws layout (4B elems): counts[N] | offsets[N+1] | cursor[N] | blockSums[256]
    //                     | ssrc[E] | pad | wT[128*128] (16B-aligned)
    const size_t ints_before = (size_t)N + (N + 1) + N + 256 + E;
    const size_t wT_off = (ints_before + 3) & ~(size_t)3;
    const size_t ws_needed = (wT_off + (size_t)F * F) * sizeof(int);

    if (ws_size >= ws_needed && NB <= 256) {
        int* counts    = (int*)d_ws;
        int* offsets   = counts + N;
        int* cursor    = offsets + (N + 1);
        int* blockSums = cursor + N;
        int* ssrc      = blockSums + 256;
        float* wT      = (float*)d_ws + wT_off;

        transpose_w_kernel<<<64, 256, 0, stream>>>(W, wT);
        zero_int_kernel<<<(N + 255) / 256, 256, 0, stream>>>(counts, N);
        hist_kernel<<<(E + 255) / 256, 256, 0, stream>>>(dst, counts, E);
        scan1_kernel<<<NB, 256, 0, stream>>>(counts, offsets, blockSums, N);
        scan2_kernel<<<1, 256, 0, stream>>>(blockSums, offsets, NB, N);
        scan3_kernel<<<(N + 255) / 256, 256, 0, stream>>>(offsets, cursor, blockSums, N);
        place_kernel<<<(E + 255) / 256, 256, 0, stream>>>(src, dst, cursor, ssrc, E);
        agg_kernel<<<2048, 256, 0, stream>>>(feat, ssrc, offsets, out, N);
        linear_relu_kernel<<<(N + ROWS2 - 1) / ROWS2, 256, 0, stream>>>(out, wT, b, N);
    } else {
        const int n4 = N * (F / 4);
        zero_f4_kernel<<<(n4 + 255) / 256, 256, 0, stream>>>((float4*)out, n4);
        const int sthreads = E * 32;
        scatter_atomic_kernel<<<(sthreads + 255) / 256, 256, 0, stream>>>(feat, src, dst, out, E);
        linear_relu_w_kernel<<<(N + 63) / 64, 256, 0, stream>>>(out, W, b, N);
    }
}